// Round 1
// baseline (304.807 us; speedup 1.0000x reference)
//
#include <hip/hip_runtime.h>

// Round 13: 8-way replicated degree histograms to kill device-scope atomic
// contention in prep (was 192-480 serialized RMWs per cacheline; prep showed
// 61us @ 16% HBM, VALU 1.8% -> atomic stall). Copy c = blockIdx&7 in both
// prep and fill; new basescan_kernel exclusive-scans the 8 copies per node
// (bases written in place, total into copy-0 slot so scan2 is unchanged).
// Everything else identical to Round 12 (pure-bf16 activations, fp32 MFMA
// accum, two-stage 32KB W staging).

typedef unsigned short u16;
typedef unsigned int u32;
typedef __attribute__((ext_vector_type(8))) short bf16x8;
typedef __attribute__((ext_vector_type(4))) float f32x4;

__device__ __forceinline__ float bf2f(u16 h) {
    union { u32 u; float f; } v; v.u = ((u32)h) << 16; return v.f;
}
__device__ __forceinline__ u16 f2bf(float f) {
    union { float f; u32 u; } v; v.f = f;
    u32 lsb = (v.u >> 16) & 1u;
    v.u += 0x7fffu + lsb;           // RNE
    return (u16)(v.u >> 16);
}

// ---------------- prep megakernel: hist | xm->bf16 | xd->bf16 | wfrag --------
// Histogram uses 8 replicated copies: deg_X[c*N + node], c = blockIdx & 7.
__global__ __launch_bounds__(256)
void prep_kernel(const int* __restrict__ dst_m, const int* __restrict__ dst_b,
                 int* __restrict__ deg_m, int* __restrict__ deg_b,
                 int* __restrict__ rank_m, int* __restrict__ rank_b, int E,
                 int NM, int ND,
                 const float* __restrict__ xm, u16* __restrict__ xm_bf, int n8m,
                 const float* __restrict__ xd, u16* __restrict__ xd_bf, int n8d,
                 const float* __restrict__ w0, const float* __restrict__ w1,
                 const float* __restrict__ w2, const float* __restrict__ w3,
                 const float* __restrict__ w4, const float* __restrict__ w5,
                 const float* __restrict__ w6, u16* __restrict__ wbuf,
                 int HB, int TB, int TB2)
{
    const int b = blockIdx.x;
    if (b < HB) {
        const int c = b & 7;
        int t = b * 256 + threadIdx.x;
        if (t < E) {
            rank_m[t] = atomicAdd(&deg_m[c * NM + dst_m[t]], 1);
        } else if (t < 2 * E) {
            int e = t - E;
            rank_b[e] = atomicAdd(&deg_b[c * ND + dst_b[e]], 1);
        }
    } else if (b < HB + TB + TB2) {
        const bool isM = b < HB + TB;
        const float* src = isM ? xm : xd;
        u16* dst = isM ? xm_bf : xd_bf;
        int n8 = isM ? n8m : n8d;
        int i = (b - (isM ? HB : HB + TB)) * 256 + threadIdx.x;
        if (i >= n8) return;
        float4 a = ((const float4*)src)[2 * i];
        float4 c2 = ((const float4*)src)[2 * i + 1];
        ushort4 h0; h0.x = f2bf(a.x); h0.y = f2bf(a.y); h0.z = f2bf(a.z); h0.w = f2bf(a.w);
        ushort4 h1; h1.x = f2bf(c2.x); h1.y = f2bf(c2.y); h1.z = f2bf(c2.z); h1.w = f2bf(c2.w);
        ((ushort4*)dst)[2 * i]     = h0;
        ((ushort4*)dst)[2 * i + 1] = h1;
    } else {
        int bb = b - HB - TB - TB2;
        const int widx = bb >> 6;
        const int o    = ((bb & 63) << 8) + threadIdx.x;
        const int OC   = (widx == 6) ? 64 : 128;
        if (o >= OC * 128) return;
        const float* W;
        switch (widx) {
            case 0: W = w0; break; case 1: W = w1; break; case 2: W = w2; break;
            case 3: W = w3; break; case 4: W = w4; break; case 5: W = w5; break;
            default: W = w6;
        }
        int j = o & 7;
        int lane = (o >> 3) & 63;
        int n, c;
        if (OC == 128) { n = (o >> 9) & 7; c = o >> 12; }
        else           { n = (o >> 9) & 3; c = o >> 11; }
        int col = n * 16 + (lane & 15);
        int k   = c * 32 + (lane >> 4) * 8 + j;
        wbuf[widx * 16384 + o] = f2bf(W[k * OC + col]);
    }
}

// ---------------- per-node scan over the 8 histogram copies ----------------
// After: deg_X[0*N+node] = total degree; deg_X[c*N+node] (c>=1) = exclusive
// base of copy c within the node's edge segment (base of copy 0 == 0).
__global__ __launch_bounds__(256)
void basescan_kernel(int* __restrict__ deg_m, int* __restrict__ deg_b,
                     int NM, int ND)
{
    int i = blockIdx.x * 256 + threadIdx.x;
    int* deg; int N; int node;
    if (i < NM)            { deg = deg_m; N = NM; node = i; }
    else if (i < NM + ND)  { deg = deg_b; N = ND; node = i - NM; }
    else return;
    int v[8];
#pragma unroll
    for (int c = 0; c < 8; ++c) v[c] = deg[c * N + node];
    int run = v[0];
#pragma unroll
    for (int c = 1; c < 8; ++c) { int t = v[c]; deg[c * N + node] = run; run += t; }
    deg[node] = run;   // total into copy-0 slot
}

__device__ __forceinline__ int wave_incl_scan(int v, int lane) {
#pragma unroll
    for (int off = 1; off < 64; off <<= 1) {
        int t = __shfl_up(v, off, 64);
        if (lane >= off) v += t;
    }
    return v;
}

// exclusive scan + sentinel, 4 elems/thread
__global__ __launch_bounds__(1024)
void scan2_kernel(const int* __restrict__ degA, int* __restrict__ rpA, int nA,
                  const int* __restrict__ degB, int* __restrict__ rpB, int nB)
{
    const int* deg = blockIdx.x ? degB : degA;
    int* rp = blockIdx.x ? rpB : rpA;
    int n = blockIdx.x ? nB : nA;

    __shared__ int wsum[16];
    __shared__ int carry;
    const int tid = threadIdx.x, lane = tid & 63, wid = tid >> 6;
    if (tid == 0) carry = 0;
    __syncthreads();

    for (int base = 0; base < n; base += 4096) {
        int idx = base + tid * 4;
        int4 v = make_int4(0, 0, 0, 0);
        if (idx + 3 < n) v = *(const int4*)(deg + idx);
        else {
            if (idx + 0 < n) v.x = deg[idx + 0];
            if (idx + 1 < n) v.y = deg[idx + 1];
            if (idx + 2 < n) v.z = deg[idx + 2];
            if (idx + 3 < n) v.w = deg[idx + 3];
        }
        int s = v.x + v.y + v.z + v.w;
        int incl = wave_incl_scan(s, lane);
        if (lane == 63) wsum[wid] = incl;
        __syncthreads();
        if (wid == 0) {
            int t = (lane < 16) ? wsum[lane] : 0;
            int ti = wave_incl_scan(t, lane);
            if (lane < 16) wsum[lane] = ti - t;
        }
        __syncthreads();
        int base_t = carry + wsum[wid] + incl - s;
        if (idx + 3 < n) {
            int4 st;
            st.x = base_t;
            st.y = base_t + v.x;
            st.z = base_t + v.x + v.y;
            st.w = base_t + v.x + v.y + v.z;
            *(int4*)(rp + idx) = st;
        } else {
            if (idx + 0 < n) rp[idx + 0] = base_t;
            if (idx + 1 < n) rp[idx + 1] = base_t + v.x;
            if (idx + 2 < n) rp[idx + 2] = base_t + v.x + v.y;
            if (idx + 3 < n) rp[idx + 3] = base_t + v.x + v.y + v.z;
        }
        __syncthreads();
        if (tid == 1023) carry += wsum[15] + incl;
        __syncthreads();
    }
    if (tid == 0) rp[n] = carry;
}

// ---------------- atomic-free fill ----------------
// pos = rp[dst] + base_c[dst] + rank_within_copy; c = blockIdx & 7 (same
// block->t mapping as prep's histogram phase).
__global__ __launch_bounds__(256)
void fill_kernel(const int* __restrict__ src_m, const int* __restrict__ dst_m,
                 const int* __restrict__ src_b, const int* __restrict__ dst_b,
                 const float* __restrict__ edge_w,
                 const int* __restrict__ rp_m, const int* __restrict__ rp_b,
                 const int* __restrict__ rank_m, const int* __restrict__ rank_b,
                 const int* __restrict__ deg_m, const int* __restrict__ deg_b,
                 int NM, int ND,
                 int* __restrict__ srcs_m, int2* __restrict__ edges_b, int E)
{
    const int c = blockIdx.x & 7;
    int t = blockIdx.x * 256 + threadIdx.x;
    if (t < E) {
        int d = dst_m[t];
        int base = c ? deg_m[c * NM + d] : 0;
        int pos = rp_m[d] + base + rank_m[t];
        srcs_m[pos] = src_m[t];
    } else if (t < 2 * E) {
        int e = t - E;
        int d = dst_b[e];
        int base = c ? deg_b[c * ND + d] : 0;
        int pos = rp_b[d] + base + rank_b[e];
        float x = edge_w[e];
        int2 pk;
        pk.x = src_b[e];
        pk.y = __float_as_int(1.0f / (1.0f + __expf(-x)));
        edges_b[pos] = pk;
    }
}

// ---------------- merged gather1+2 from bf16 rows -> bf16 agg ----------------
__global__ __launch_bounds__(256)
void gather12(const u16* __restrict__ Xb,
              const int* __restrict__ srcs_m, const int2* __restrict__ edges_b,
              const int* __restrict__ rp_m, const int* __restrict__ rp_b,
              u16* __restrict__ agg1, u16* __restrict__ agg2, int NM, int ND)
{
    const int h  = blockIdx.x * 8 + (threadIdx.x >> 5);
    const int cl = threadIdx.x & 31;
    float4 acc = make_float4(0.f, 0.f, 0.f, 0.f);

    if (h < NM) {
        int i   = rp_m[h];
        int end = rp_m[h + 1];
        for (; i + 4 <= end; i += 4) {
            int s0 = srcs_m[i], s1 = srcs_m[i + 1], s2 = srcs_m[i + 2], s3 = srcs_m[i + 3];
            ushort4 v0 = *(const ushort4*)(Xb + (size_t)s0 * 128 + cl * 4);
            ushort4 v1 = *(const ushort4*)(Xb + (size_t)s1 * 128 + cl * 4);
            ushort4 v2 = *(const ushort4*)(Xb + (size_t)s2 * 128 + cl * 4);
            ushort4 v3 = *(const ushort4*)(Xb + (size_t)s3 * 128 + cl * 4);
            acc.x += (bf2f(v0.x) + bf2f(v1.x)) + (bf2f(v2.x) + bf2f(v3.x));
            acc.y += (bf2f(v0.y) + bf2f(v1.y)) + (bf2f(v2.y) + bf2f(v3.y));
            acc.z += (bf2f(v0.z) + bf2f(v1.z)) + (bf2f(v2.z) + bf2f(v3.z));
            acc.w += (bf2f(v0.w) + bf2f(v1.w)) + (bf2f(v2.w) + bf2f(v3.w));
        }
        for (; i < end; ++i) {
            int s = srcs_m[i];
            ushort4 v = *(const ushort4*)(Xb + (size_t)s * 128 + cl * 4);
            acc.x += bf2f(v.x); acc.y += bf2f(v.y);
            acc.z += bf2f(v.z); acc.w += bf2f(v.w);
        }
        ushort4 st;
        st.x = f2bf(acc.x); st.y = f2bf(acc.y);
        st.z = f2bf(acc.z); st.w = f2bf(acc.w);
        *(ushort4*)(agg1 + (size_t)h * 128 + cl * 4) = st;
    } else if (h < NM + ND) {
        int node = h - NM;
        int i   = rp_b[node];
        int end = rp_b[node + 1];
        for (; i + 4 <= end; i += 4) {
            int2 p0 = edges_b[i],     p1 = edges_b[i + 1];
            int2 p2 = edges_b[i + 2], p3 = edges_b[i + 3];
            float w0 = __int_as_float(p0.y), w1 = __int_as_float(p1.y);
            float w2 = __int_as_float(p2.y), w3 = __int_as_float(p3.y);
            ushort4 v0 = *(const ushort4*)(Xb + (size_t)p0.x * 128 + cl * 4);
            ushort4 v1 = *(const ushort4*)(Xb + (size_t)p1.x * 128 + cl * 4);
            ushort4 v2 = *(const ushort4*)(Xb + (size_t)p2.x * 128 + cl * 4);
            ushort4 v3 = *(const ushort4*)(Xb + (size_t)p3.x * 128 + cl * 4);
            acc.x = fmaf(w0, bf2f(v0.x), acc.x); acc.y = fmaf(w0, bf2f(v0.y), acc.y);
            acc.z = fmaf(w0, bf2f(v0.z), acc.z); acc.w = fmaf(w0, bf2f(v0.w), acc.w);
            acc.x = fmaf(w1, bf2f(v1.x), acc.x); acc.y = fmaf(w1, bf2f(v1.y), acc.y);
            acc.z = fmaf(w1, bf2f(v1.z), acc.z); acc.w = fmaf(w1, bf2f(v1.w), acc.w);
            acc.x = fmaf(w2, bf2f(v2.x), acc.x); acc.y = fmaf(w2, bf2f(v2.y), acc.y);
            acc.z = fmaf(w2, bf2f(v2.z), acc.z); acc.w = fmaf(w2, bf2f(v2.w), acc.w);
            acc.x = fmaf(w3, bf2f(v3.x), acc.x); acc.y = fmaf(w3, bf2f(v3.y), acc.y);
            acc.z = fmaf(w3, bf2f(v3.z), acc.z); acc.w = fmaf(w3, bf2f(v3.w), acc.w);
        }
        for (; i < end; ++i) {
            int2 pk = edges_b[i];
            float w = __int_as_float(pk.y);
            ushort4 v = *(const ushort4*)(Xb + (size_t)pk.x * 128 + cl * 4);
            acc.x = fmaf(w, bf2f(v.x), acc.x); acc.y = fmaf(w, bf2f(v.y), acc.y);
            acc.z = fmaf(w, bf2f(v.z), acc.z); acc.w = fmaf(w, bf2f(v.w), acc.w);
        }
        ushort4 st;
        st.x = f2bf(acc.x); st.y = f2bf(acc.y);
        st.z = f2bf(acc.z); st.w = f2bf(acc.w);
        *(ushort4*)(agg2 + (size_t)node * 128 + cl * 4) = st;
    }
}

// ---------------- gather3: bf16 movie rows -> bf16 agg3, weighted ----------
__global__ __launch_bounds__(256)
void gather3_kernel(const u16* __restrict__ Mv, const int2* __restrict__ edges_b,
                    const int* __restrict__ rp_b, u16* __restrict__ agg3, int ND)
{
    const int node = blockIdx.x * 8 + (threadIdx.x >> 5);
    if (node >= ND) return;
    const int cl = threadIdx.x & 31;
    int i   = rp_b[node];
    int end = rp_b[node + 1];

    float4 acc = make_float4(0.f, 0.f, 0.f, 0.f);
    for (; i + 4 <= end; i += 4) {
        int2 p0 = edges_b[i],     p1 = edges_b[i + 1];
        int2 p2 = edges_b[i + 2], p3 = edges_b[i + 3];
        float w0 = __int_as_float(p0.y), w1 = __int_as_float(p1.y);
        float w2 = __int_as_float(p2.y), w3 = __int_as_float(p3.y);
        ushort4 v0 = *(const ushort4*)(Mv + (size_t)p0.x * 128 + cl * 4);
        ushort4 v1 = *(const ushort4*)(Mv + (size_t)p1.x * 128 + cl * 4);
        ushort4 v2 = *(const ushort4*)(Mv + (size_t)p2.x * 128 + cl * 4);
        ushort4 v3 = *(const ushort4*)(Mv + (size_t)p3.x * 128 + cl * 4);
        acc.x = fmaf(w0, bf2f(v0.x), acc.x); acc.y = fmaf(w0, bf2f(v0.y), acc.y);
        acc.z = fmaf(w0, bf2f(v0.z), acc.z); acc.w = fmaf(w0, bf2f(v0.w), acc.w);
        acc.x = fmaf(w1, bf2f(v1.x), acc.x); acc.y = fmaf(w1, bf2f(v1.y), acc.y);
        acc.z = fmaf(w1, bf2f(v1.z), acc.z); acc.w = fmaf(w1, bf2f(v1.w), acc.w);
        acc.x = fmaf(w2, bf2f(v2.x), acc.x); acc.y = fmaf(w2, bf2f(v2.y), acc.y);
        acc.z = fmaf(w2, bf2f(v2.z), acc.z); acc.w = fmaf(w2, bf2f(v2.w), acc.w);
        acc.x = fmaf(w3, bf2f(v3.x), acc.x); acc.y = fmaf(w3, bf2f(v3.y), acc.y);
        acc.z = fmaf(w3, bf2f(v3.z), acc.z); acc.w = fmaf(w3, bf2f(v3.w), acc.w);
    }
    for (; i < end; ++i) {
        int2 pk = edges_b[i];
        float w = __int_as_float(pk.y);
        ushort4 v = *(const ushort4*)(Mv + (size_t)pk.x * 128 + cl * 4);
        acc.x = fmaf(w, bf2f(v.x), acc.x); acc.y = fmaf(w, bf2f(v.y), acc.y);
        acc.z = fmaf(w, bf2f(v.z), acc.z); acc.w = fmaf(w, bf2f(v.w), acc.w);
    }
    ushort4 st;
    st.x = f2bf(acc.x); st.y = f2bf(acc.y);
    st.z = f2bf(acc.z); st.w = f2bf(acc.w);
    *(ushort4*)(agg3 + (size_t)node * 128 + cl * 4) = st;
}

// ---------------- merged MFMA conv1+conv2 (bf16 A, two-stage 32KB W) --------
// No early returns: barriers mid-kernel; rows clamped, stores guarded.
__global__ __launch_bounds__(256)
void conv12_mfma(const u16* __restrict__ agg1, const u16* __restrict__ w1r,
                 const float* __restrict__ b1, const u16* __restrict__ xm_bf,
                 const u16* __restrict__ w1o, u16* __restrict__ C1, int N1, int cb1,
                 const u16* __restrict__ agg2, const u16* __restrict__ w2r,
                 const float* __restrict__ b2, const u16* __restrict__ xd_bf,
                 const u16* __restrict__ w2o, u16* __restrict__ C2, int N2)
{
    __shared__ u16 sW[16384];   // 32 KB, one phase at a time

    const bool seg1 = (int)blockIdx.x < cb1;
    const u16 *A0, *A1p, *Wr, *Wo; const float* bias; u16* C; int N, base;
    if (seg1) { A0 = agg1; A1p = xm_bf; Wr = w1r; Wo = w1o; bias = b1; C = C1; N = N1; base = blockIdx.x; }
    else      { A0 = agg2; A1p = xd_bf; Wr = w2r; Wo = w2o; bias = b2; C = C2; N = N2; base = blockIdx.x - cb1; }

    const int tid  = threadIdx.x;
    const int lane = tid & 63;
    const int m0   = (base * 4 + (tid >> 6)) * 32;
    const int lr   = lane & 15;
    const int quad = lane >> 4;

    int r0 = m0 + lr;      if (r0 >= N) r0 = N - 1;
    int r1 = m0 + 16 + lr; if (r1 >= N) r1 = N - 1;

    f32x4 acc[2][8];
#pragma unroll
    for (int mt = 0; mt < 2; ++mt)
#pragma unroll
        for (int n = 0; n < 8; ++n) acc[mt][n] = (f32x4){0.f, 0.f, 0.f, 0.f};

    // phase 0: aggregate term
    for (int i = tid; i < 2048; i += 256)
        ((uint4*)sW)[i] = ((const uint4*)Wr)[i];
    __syncthreads();
#pragma unroll
    for (int c = 0; c < 4; ++c) {
        const int kb = c * 32 + quad * 8;
        bf16x8 a0 = *(const bf16x8*)(A0 + (size_t)r0 * 128 + kb);
        bf16x8 a1 = *(const bf16x8*)(A0 + (size_t)r1 * 128 + kb);
        const u16* wp = sW + c * 4096 + lane * 8;
#pragma unroll
        for (int n = 0; n < 8; ++n) {
            bf16x8 b = *(const bf16x8*)(wp + n * 512);
            acc[0][n] = __builtin_amdgcn_mfma_f32_16x16x32_bf16(a0, b, acc[0][n], 0, 0, 0);
            acc[1][n] = __builtin_amdgcn_mfma_f32_16x16x32_bf16(a1, b, acc[1][n], 0, 0, 0);
        }
    }
    __syncthreads();

    // phase 1: root term
    for (int i = tid; i < 2048; i += 256)
        ((uint4*)sW)[i] = ((const uint4*)Wo)[i];
    __syncthreads();
#pragma unroll
    for (int c = 0; c < 4; ++c) {
        const int kb = c * 32 + quad * 8;
        bf16x8 a0 = *(const bf16x8*)(A1p + (size_t)r0 * 128 + kb);
        bf16x8 a1 = *(const bf16x8*)(A1p + (size_t)r1 * 128 + kb);
        const u16* wp = sW + c * 4096 + lane * 8;
#pragma unroll
        for (int n = 0; n < 8; ++n) {
            bf16x8 b = *(const bf16x8*)(wp + n * 512);
            acc[0][n] = __builtin_amdgcn_mfma_f32_16x16x32_bf16(a0, b, acc[0][n], 0, 0, 0);
            acc[1][n] = __builtin_amdgcn_mfma_f32_16x16x32_bf16(a1, b, acc[1][n], 0, 0, 0);
        }
    }

#pragma unroll
    for (int mt = 0; mt < 2; ++mt) {
#pragma unroll
        for (int n = 0; n < 8; ++n) {
            const int col = n * 16 + lr;
            const float b = bias[col];
#pragma unroll
            for (int r = 0; r < 4; ++r) {
                int row = m0 + mt * 16 + quad * 4 + r;
                if (row >= N) continue;
                C[(size_t)row * 128 + col] = f2bf(fmaxf(acc[mt][n][r] + b, 0.f));
            }
        }
    }
}

// ---------------- conv3 + lin fused (bf16 A), 50 KB LDS ----------------
__global__ __launch_bounds__(256)
void conv3_lin(const u16* __restrict__ A1, const u16* __restrict__ Wr,
               const float* __restrict__ bias3,
               const u16* __restrict__ A2, const u16* __restrict__ Wo,
               const u16* __restrict__ Wl, const float* __restrict__ bias_l,
               float* __restrict__ out, int N)
{
    __shared__ u16 lds[17408 + 8192];   // 34 KB tile region (overlays conv W) + 16 KB lin W
    u16* tile = lds;
    u16* sWl  = lds + 17408;

    const int tid  = threadIdx.x;
    const int lane = tid & 63;
    const int wv   = tid >> 6;
    const int wbase = wv * 32;
    const int m0   = (blockIdx.x * 4 + wv) * 32;
    const int lr   = lane & 15;
    const int quad = lane >> 4;

    int r0 = m0 + lr;      if (r0 >= N) r0 = N - 1;
    int r1 = m0 + 16 + lr; if (r1 >= N) r1 = N - 1;

    f32x4 acc[2][8];
#pragma unroll
    for (int mt = 0; mt < 2; ++mt)
#pragma unroll
        for (int n = 0; n < 8; ++n) acc[mt][n] = (f32x4){0.f, 0.f, 0.f, 0.f};

    // stage lin W once + conv phase-0 W
    for (int i = tid; i < 1024; i += 256)
        ((uint4*)sWl)[i] = ((const uint4*)Wl)[i];
    for (int i = tid; i < 2048; i += 256)
        ((uint4*)lds)[i] = ((const uint4*)Wr)[i];
    __syncthreads();
#pragma unroll
    for (int c = 0; c < 4; ++c) {
        const int kb = c * 32 + quad * 8;
        bf16x8 a0 = *(const bf16x8*)(A1 + (size_t)r0 * 128 + kb);
        bf16x8 a1 = *(const bf16x8*)(A1 + (size_t)r1 * 128 + kb);
        const u16* wp = lds + c * 4096 + lane * 8;
#pragma unroll
        for (int n = 0; n < 8; ++n) {
            bf16x8 b = *(const bf16x8*)(wp + n * 512);
            acc[0][n] = __builtin_amdgcn_mfma_f32_16x16x32_bf16(a0, b, acc[0][n], 0, 0, 0);
            acc[1][n] = __builtin_amdgcn_mfma_f32_16x16x32_bf16(a1, b, acc[1][n], 0, 0, 0);
        }
    }
    __syncthreads();
    for (int i = tid; i < 2048; i += 256)
        ((uint4*)lds)[i] = ((const uint4*)Wo)[i];
    __syncthreads();
#pragma unroll
    for (int c = 0; c < 4; ++c) {
        const int kb = c * 32 + quad * 8;
        bf16x8 a0 = *(const bf16x8*)(A2 + (size_t)r0 * 128 + kb);
        bf16x8 a1 = *(const bf16x8*)(A2 + (size_t)r1 * 128 + kb);
        const u16* wp = lds + c * 4096 + lane * 8;
#pragma unroll
        for (int n = 0; n < 8; ++n) {
            bf16x8 b = *(const bf16x8*)(wp + n * 512);
            acc[0][n] = __builtin_amdgcn_mfma_f32_16x16x32_bf16(a0, b, acc[0][n], 0, 0, 0);
            acc[1][n] = __builtin_amdgcn_mfma_f32_16x16x32_bf16(a1, b, acc[1][n], 0, 0, 0);
        }
    }
    __syncthreads();   // done reading conv W; tile overlays it

    // relu'd bf16 tile, C-layout -> padded rows (pitch 136)
#pragma unroll
    for (int mt = 0; mt < 2; ++mt) {
#pragma unroll
        for (int n = 0; n < 8; ++n) {
            const int col = n * 16 + lr;
            const float b = bias3[col];
#pragma unroll
            for (int r = 0; r < 4; ++r) {
                int row = wbase + mt * 16 + quad * 4 + r;
                tile[row * 136 + col] = f2bf(fmaxf(acc[mt][n][r] + b, 0.f));
            }
        }
    }
    __syncthreads();

    f32x4 acc2[2][4];
#pragma unroll
    for (int mt = 0; mt < 2; ++mt)
#pragma unroll
        for (int n = 0; n < 4; ++n) acc2[mt][n] = (f32x4){0.f, 0.f, 0.f, 0.f};

#pragma unroll
    for (int c = 0; c < 4; ++c) {
        const int kb = c * 32 + quad * 8;
        bf16x8 a0 = *(const bf16x8*)(tile + (wbase + lr) * 136 + kb);
        bf16x8 a1 = *(const bf16x8*)(tile + (wbase + 16 + lr) * 136 + kb);
#pragma unroll
        for (int n = 0; n < 4; ++n) {
            bf16x8 b = *(const bf16x8*)(sWl + c * 2048 + n * 512 + lane * 8);
            acc2[0][n] = __builtin_amdgcn_mfma_f32_16x16x32_bf16(a0, b, acc2[0][n], 0, 0, 0);
            acc2[1][n] = __builtin_amdgcn_mfma_f32_16x16x32_bf16(a1, b, acc2[1][n], 0, 0, 0);
        }
    }

#pragma unroll
    for (int mt = 0; mt < 2; ++mt) {
#pragma unroll
        for (int n = 0; n < 4; ++n) {
            const int col = n * 16 + lr;
            const float b = bias_l[col];
#pragma unroll
            for (int r = 0; r < 4; ++r) {
                int row = m0 + mt * 16 + quad * 4 + r;
                if (row >= N) continue;
                out[(size_t)row * 64 + col] = acc2[mt][n][r] + b;
            }
        }
    }
}

extern "C" void kernel_launch(void* const* d_in, const int* in_sizes, int n_in,
                              void* d_out, int out_size, void* d_ws, size_t ws_size,
                              hipStream_t stream)
{
    const float* x_meas  = (const float*)d_in[0];
    const float* x_dem   = (const float*)d_in[1];
    const int*   src_m   = (const int*)d_in[2];
    const int*   dst_m   = (const int*)d_in[3];
    const int*   src_b   = (const int*)d_in[4];
    const int*   dst_b   = (const int*)d_in[5];
    const float* edge_w  = (const float*)d_in[6];
    const float* W_rel1  = (const float*)d_in[7];
    const float* b_rel1  = (const float*)d_in[8];
    const float* W_root1 = (const float*)d_in[9];
    const float* W_rel2  = (const float*)d_in[10];
    const float* b_rel2  = (const float*)d_in[11];
    const float* W_root2 = (const float*)d_in[12];
    const float* W_rel3  = (const float*)d_in[13];
    const float* b_rel3  = (const float*)d_in[14];
    const float* W_root3 = (const float*)d_in[15];
    const float* W_lin   = (const float*)d_in[16];
    const float* b_lin   = (const float*)d_in[17];
    float* out = (float*)d_out;

    const int NM = 50000, ND = 20000, E = 600000;

    char* p = (char*)d_ws;
    auto alloc = [&](size_t bytes) { char* r = p; p += (bytes + 511) & ~(size_t)511; return r; };
    int*   deg_m   = (int*)alloc((size_t)8 * NM * 4);     // 8 replicated copies
    int*   deg_b   = (int*)alloc((size_t)8 * ND * 4);
    int*   rp_m    = (int*)alloc((size_t)(NM + 1) * 4);
    int*   rp_b    = (int*)alloc((size_t)(ND + 1) * 4);
    int*   srcs_m  = (int*)alloc((size_t)E * 4);
    int2*  edges_b = (int2*)alloc((size_t)E * 8);
    u16*   agg1    = (u16*)alloc((size_t)NM * 128 * 2);   // 12.8 MB bf16
    u16*   agg2    = (u16*)alloc((size_t)ND * 128 * 2);   // 5.12 MB
    u16*   movie   = (u16*)alloc((size_t)NM * 128 * 2);   // 12.8 MB (= xm_bf alias)
    u16*   t2      = (u16*)alloc((size_t)ND * 128 * 2);   // 5.12 MB
    u16*   xd_bf   = (u16*)alloc((size_t)ND * 128 * 2);   // 5.12 MB
    u16*   wbuf    = (u16*)alloc(7 * 16384 * 2);          // 224 KB
    // aliases (stream-serial lifetimes):
    int* rank_m = (int*)agg1;          // dies at fill; agg1 written by gather12
    int* rank_b = rank_m + E;          // 4.8 MB total <= 12.8 MB
    u16* xm_bf  = movie;               // conv1 reads own rows, writes own rows (safe)
    u16* agg3   = agg1;                // agg1 dead after conv12

    size_t deg_span = (size_t)((char*)deg_b - (char*)deg_m) + (size_t)8 * ND * 4;
    hipMemsetAsync(deg_m, 0, deg_span, stream);

    const int HB  = (2 * E + 255) / 256;       // 4688
    const int TB  = (NM * 16 + 255) / 256;     // 3125
    const int TB2 = (ND * 16 + 255) / 256;     // 1250
    const int WB  = 448;
    prep_kernel<<<HB + TB + TB2 + WB, 256, 0, stream>>>(
        dst_m, dst_b, deg_m, deg_b, rank_m, rank_b, E, NM, ND,
        x_meas, xm_bf, NM * 16, x_dem, xd_bf, ND * 16,
        W_rel1, W_root1, W_rel2, W_root2, W_rel3, W_root3, W_lin, wbuf,
        HB, TB, TB2);

    basescan_kernel<<<(NM + ND + 255) / 256, 256, 0, stream>>>(deg_m, deg_b, NM, ND);
    scan2_kernel<<<2, 1024, 0, stream>>>(deg_m, rp_m, NM, deg_b, rp_b, ND);
    fill_kernel<<<HB, 256, 0, stream>>>(src_m, dst_m, src_b, dst_b, edge_w,
                                        rp_m, rp_b, rank_m, rank_b,
                                        deg_m, deg_b, NM, ND, srcs_m, edges_b, E);

    gather12<<<(NM + ND + 7) / 8, 256, 0, stream>>>(xm_bf, srcs_m, edges_b,
                                                    rp_m, rp_b, agg1, agg2, NM, ND);

    const int cb1 = (NM + 127) / 128;
    const int cb2 = (ND + 127) / 128;
    u16* w1r = wbuf + 0 * 16384; u16* w1o = wbuf + 1 * 16384;
    u16* w2r = wbuf + 2 * 16384; u16* w2o = wbuf + 3 * 16384;
    u16* w3r = wbuf + 4 * 16384; u16* w3o = wbuf + 5 * 16384;
    u16* wl  = wbuf + 6 * 16384;
    conv12_mfma<<<cb1 + cb2, 256, 0, stream>>>(agg1, w1r, b_rel1, xm_bf, w1o, movie, NM, cb1,
                                               agg2, w2r, b_rel2, xd_bf, w2o, t2,    ND);

    gather3_kernel<<<(ND + 7) / 8, 256, 0, stream>>>(movie, edges_b, rp_b, agg3, ND);

    conv3_lin<<<cb2, 256, 0, stream>>>(agg3, w3r, b_rel3, t2, w3o, wl, b_lin, out, ND);
}

// Round 2
// 303.443 us; speedup vs baseline: 1.0045x; 1.0045x over previous
//
#include <hip/hip_runtime.h>

// Round 14: eliminate global scattered atomics entirely. Evidence: R13's 8-way
// replication left dur and WRITE_SIZE unchanged (59.6 MB, = 1.2M atomics x
// 32B) -> raw atomic-path throughput bound (~21 G/s), not contention.
// New hist_lds kernel: 64 movie blocks / 32 dem blocks, each owns an
// exclusive edge chunk and builds a private LDS histogram (u16-packed,
// 100 KB), LDS atomicAdd returns rank-within-copy; copies dumped to global
// (7.7 MB streaming). basescan2 scans copies per node; fill adds the copy
// base. Global memset dropped (nothing needs pre-zeroing). Conversion +
// W-fragging split into prep2 (unchanged logic). Rest identical to R13.

typedef unsigned short u16;
typedef unsigned int u32;
typedef __attribute__((ext_vector_type(8))) short bf16x8;
typedef __attribute__((ext_vector_type(4))) float f32x4;

#define NMC 50000
#define NDC 20000
#define EC  600000
#define CM  64          // movie histogram copies
#define CD  32          // dem histogram copies
#define CHM (EC / CM)   // 9375
#define CHD (EC / CD)   // 18750
#define NWM (NMC / 2)   // 25000 packed words
#define NWD (NDC / 2)   // 10000

__device__ __forceinline__ float bf2f(u16 h) {
    union { u32 u; float f; } v; v.u = ((u32)h) << 16; return v.f;
}
__device__ __forceinline__ u16 f2bf(float f) {
    union { float f; u32 u; } v; v.f = f;
    u32 lsb = (v.u >> 16) & 1u;
    v.u += 0x7fffu + lsb;           // RNE
    return (u16)(v.u >> 16);
}

// ---------------- LDS histogram + rank (no global atomics) ----------------
__global__ __launch_bounds__(256)
void hist_lds(const int* __restrict__ dst_m, const int* __restrict__ dst_b,
              int* __restrict__ rank_m, int* __restrict__ rank_b,
              u32* __restrict__ histm, u32* __restrict__ histd)
{
    __shared__ u32 h[NWM];          // 100 KB; dem blocks use first NWD words
    const int b = blockIdx.x;
    const bool isM = b < CM;
    const int nw = isM ? NWM : NWD;
    for (int i = threadIdx.x; i < nw; i += 256) h[i] = 0;
    __syncthreads();
    if (isM) {
        const int e0 = b * CHM;
        const int e1 = min(EC, e0 + CHM);
        for (int e = e0 + threadIdx.x; e < e1; e += 256) {
            int d = dst_m[e];
            int sh = (d & 1) * 16;
            u32 old = atomicAdd(&h[d >> 1], 1u << sh);
            rank_m[e] = (old >> sh) & 0xffffu;
        }
        __syncthreads();
        for (int i = threadIdx.x; i < nw; i += 256)
            histm[(size_t)b * NWM + i] = h[i];
    } else {
        const int bb = b - CM;
        const int e0 = bb * CHD;
        const int e1 = min(EC, e0 + CHD);
        for (int e = e0 + threadIdx.x; e < e1; e += 256) {
            int d = dst_b[e];
            int sh = (d & 1) * 16;
            u32 old = atomicAdd(&h[d >> 1], 1u << sh);
            rank_b[e] = (old >> sh) & 0xffffu;
        }
        __syncthreads();
        for (int i = threadIdx.x; i < nw; i += 256)
            histd[(size_t)bb * NWD + i] = h[i];
    }
}

// ---------------- prep2: xm->bf16 | xd->bf16 | wfrag ----------------
__global__ __launch_bounds__(256)
void prep2(const float* __restrict__ xm, u16* __restrict__ xm_bf, int n8m,
           const float* __restrict__ xd, u16* __restrict__ xd_bf, int n8d,
           const float* __restrict__ w0, const float* __restrict__ w1,
           const float* __restrict__ w2, const float* __restrict__ w3,
           const float* __restrict__ w4, const float* __restrict__ w5,
           const float* __restrict__ w6, u16* __restrict__ wbuf,
           int TB, int TB2)
{
    const int b = blockIdx.x;
    if (b < TB + TB2) {
        const bool isM = b < TB;
        const float* src = isM ? xm : xd;
        u16* dst = isM ? xm_bf : xd_bf;
        int n8 = isM ? n8m : n8d;
        int i = (b - (isM ? 0 : TB)) * 256 + threadIdx.x;
        if (i >= n8) return;
        float4 a = ((const float4*)src)[2 * i];
        float4 c2 = ((const float4*)src)[2 * i + 1];
        ushort4 h0; h0.x = f2bf(a.x); h0.y = f2bf(a.y); h0.z = f2bf(a.z); h0.w = f2bf(a.w);
        ushort4 h1; h1.x = f2bf(c2.x); h1.y = f2bf(c2.y); h1.z = f2bf(c2.z); h1.w = f2bf(c2.w);
        ((ushort4*)dst)[2 * i]     = h0;
        ((ushort4*)dst)[2 * i + 1] = h1;
    } else {
        int bb = b - TB - TB2;
        const int widx = bb >> 6;
        const int o    = ((bb & 63) << 8) + threadIdx.x;
        const int OC   = (widx == 6) ? 64 : 128;
        if (o >= OC * 128) return;
        const float* W;
        switch (widx) {
            case 0: W = w0; break; case 1: W = w1; break; case 2: W = w2; break;
            case 3: W = w3; break; case 4: W = w4; break; case 5: W = w5; break;
            default: W = w6;
        }
        int j = o & 7;
        int lane = (o >> 3) & 63;
        int n, c;
        if (OC == 128) { n = (o >> 9) & 7; c = o >> 12; }
        else           { n = (o >> 9) & 3; c = o >> 11; }
        int col = n * 16 + (lane & 15);
        int k   = c * 32 + (lane >> 4) * 8 + j;
        wbuf[widx * 16384 + o] = f2bf(W[k * OC + col]);
    }
}

// ---------------- per-node scan over histogram copies (packed u16) ---------
// After: hist[c][node] (u16 half) = exclusive base of copy c; deg[node] = total.
__global__ __launch_bounds__(256)
void basescan2(u32* __restrict__ histm, u32* __restrict__ histd,
               int* __restrict__ deg_m, int* __restrict__ deg_b)
{
    int w = blockIdx.x * 256 + threadIdx.x;
    u32* hist; int* deg; int NW, C;
    if (w < NWM)            { hist = histm; deg = deg_m; NW = NWM; C = CM; }
    else if (w < NWM + NWD) { hist = histd; deg = deg_b; NW = NWD; C = CD; w -= NWM; }
    else return;
    u32 runlo = 0, runhi = 0;
    for (int c = 0; c < C; ++c) {
        u32 v = hist[(size_t)c * NW + w];
        hist[(size_t)c * NW + w] = runlo | (runhi << 16);
        runlo += v & 0xffffu;
        runhi += v >> 16;
    }
    deg[2 * w]     = (int)runlo;
    deg[2 * w + 1] = (int)runhi;
}

__device__ __forceinline__ int wave_incl_scan(int v, int lane) {
#pragma unroll
    for (int off = 1; off < 64; off <<= 1) {
        int t = __shfl_up(v, off, 64);
        if (lane >= off) v += t;
    }
    return v;
}

// exclusive scan + sentinel, 4 elems/thread
__global__ __launch_bounds__(1024)
void scan2_kernel(const int* __restrict__ degA, int* __restrict__ rpA, int nA,
                  const int* __restrict__ degB, int* __restrict__ rpB, int nB)
{
    const int* deg = blockIdx.x ? degB : degA;
    int* rp = blockIdx.x ? rpB : rpA;
    int n = blockIdx.x ? nB : nA;

    __shared__ int wsum[16];
    __shared__ int carry;
    const int tid = threadIdx.x, lane = tid & 63, wid = tid >> 6;
    if (tid == 0) carry = 0;
    __syncthreads();

    for (int base = 0; base < n; base += 4096) {
        int idx = base + tid * 4;
        int4 v = make_int4(0, 0, 0, 0);
        if (idx + 3 < n) v = *(const int4*)(deg + idx);
        else {
            if (idx + 0 < n) v.x = deg[idx + 0];
            if (idx + 1 < n) v.y = deg[idx + 1];
            if (idx + 2 < n) v.z = deg[idx + 2];
            if (idx + 3 < n) v.w = deg[idx + 3];
        }
        int s = v.x + v.y + v.z + v.w;
        int incl = wave_incl_scan(s, lane);
        if (lane == 63) wsum[wid] = incl;
        __syncthreads();
        if (wid == 0) {
            int t = (lane < 16) ? wsum[lane] : 0;
            int ti = wave_incl_scan(t, lane);
            if (lane < 16) wsum[lane] = ti - t;
        }
        __syncthreads();
        int base_t = carry + wsum[wid] + incl - s;
        if (idx + 3 < n) {
            int4 st;
            st.x = base_t;
            st.y = base_t + v.x;
            st.z = base_t + v.x + v.y;
            st.w = base_t + v.x + v.y + v.z;
            *(int4*)(rp + idx) = st;
        } else {
            if (idx + 0 < n) rp[idx + 0] = base_t;
            if (idx + 1 < n) rp[idx + 1] = base_t + v.x;
            if (idx + 2 < n) rp[idx + 2] = base_t + v.x + v.y;
            if (idx + 3 < n) rp[idx + 3] = base_t + v.x + v.y + v.z;
        }
        __syncthreads();
        if (tid == 1023) carry += wsum[15] + incl;
        __syncthreads();
    }
    if (tid == 0) rp[n] = carry;
}

// ---------------- atomic-free fill ----------------
// pos = rp[dst] + copy_base[chunk(e)][dst] + rank_within_copy.
__global__ __launch_bounds__(256)
void fill_kernel(const int* __restrict__ src_m, const int* __restrict__ dst_m,
                 const int* __restrict__ src_b, const int* __restrict__ dst_b,
                 const float* __restrict__ edge_w,
                 const int* __restrict__ rp_m, const int* __restrict__ rp_b,
                 const int* __restrict__ rank_m, const int* __restrict__ rank_b,
                 const u32* __restrict__ histm, const u32* __restrict__ histd,
                 int* __restrict__ srcs_m, int2* __restrict__ edges_b, int E)
{
    int t = blockIdx.x * 256 + threadIdx.x;
    if (t < E) {
        int d = dst_m[t];
        int c = t / CHM;
        u32 pk = histm[(size_t)c * NWM + (d >> 1)];
        int base = (pk >> ((d & 1) * 16)) & 0xffffu;
        int pos = rp_m[d] + base + rank_m[t];
        srcs_m[pos] = src_m[t];
    } else if (t < 2 * E) {
        int e = t - E;
        int d = dst_b[e];
        int c = e / CHD;
        u32 pkb = histd[(size_t)c * NWD + (d >> 1)];
        int base = (pkb >> ((d & 1) * 16)) & 0xffffu;
        int pos = rp_b[d] + base + rank_b[e];
        float x = edge_w[e];
        int2 pk;
        pk.x = src_b[e];
        pk.y = __float_as_int(1.0f / (1.0f + __expf(-x)));
        edges_b[pos] = pk;
    }
}

// ---------------- merged gather1+2 from bf16 rows -> bf16 agg ----------------
__global__ __launch_bounds__(256)
void gather12(const u16* __restrict__ Xb,
              const int* __restrict__ srcs_m, const int2* __restrict__ edges_b,
              const int* __restrict__ rp_m, const int* __restrict__ rp_b,
              u16* __restrict__ agg1, u16* __restrict__ agg2, int NM, int ND)
{
    const int h  = blockIdx.x * 8 + (threadIdx.x >> 5);
    const int cl = threadIdx.x & 31;
    float4 acc = make_float4(0.f, 0.f, 0.f, 0.f);

    if (h < NM) {
        int i   = rp_m[h];
        int end = rp_m[h + 1];
        for (; i + 4 <= end; i += 4) {
            int s0 = srcs_m[i], s1 = srcs_m[i + 1], s2 = srcs_m[i + 2], s3 = srcs_m[i + 3];
            ushort4 v0 = *(const ushort4*)(Xb + (size_t)s0 * 128 + cl * 4);
            ushort4 v1 = *(const ushort4*)(Xb + (size_t)s1 * 128 + cl * 4);
            ushort4 v2 = *(const ushort4*)(Xb + (size_t)s2 * 128 + cl * 4);
            ushort4 v3 = *(const ushort4*)(Xb + (size_t)s3 * 128 + cl * 4);
            acc.x += (bf2f(v0.x) + bf2f(v1.x)) + (bf2f(v2.x) + bf2f(v3.x));
            acc.y += (bf2f(v0.y) + bf2f(v1.y)) + (bf2f(v2.y) + bf2f(v3.y));
            acc.z += (bf2f(v0.z) + bf2f(v1.z)) + (bf2f(v2.z) + bf2f(v3.z));
            acc.w += (bf2f(v0.w) + bf2f(v1.w)) + (bf2f(v2.w) + bf2f(v3.w));
        }
        for (; i < end; ++i) {
            int s = srcs_m[i];
            ushort4 v = *(const ushort4*)(Xb + (size_t)s * 128 + cl * 4);
            acc.x += bf2f(v.x); acc.y += bf2f(v.y);
            acc.z += bf2f(v.z); acc.w += bf2f(v.w);
        }
        ushort4 st;
        st.x = f2bf(acc.x); st.y = f2bf(acc.y);
        st.z = f2bf(acc.z); st.w = f2bf(acc.w);
        *(ushort4*)(agg1 + (size_t)h * 128 + cl * 4) = st;
    } else if (h < NM + ND) {
        int node = h - NM;
        int i   = rp_b[node];
        int end = rp_b[node + 1];
        for (; i + 4 <= end; i += 4) {
            int2 p0 = edges_b[i],     p1 = edges_b[i + 1];
            int2 p2 = edges_b[i + 2], p3 = edges_b[i + 3];
            float w0 = __int_as_float(p0.y), w1 = __int_as_float(p1.y);
            float w2 = __int_as_float(p2.y), w3 = __int_as_float(p3.y);
            ushort4 v0 = *(const ushort4*)(Xb + (size_t)p0.x * 128 + cl * 4);
            ushort4 v1 = *(const ushort4*)(Xb + (size_t)p1.x * 128 + cl * 4);
            ushort4 v2 = *(const ushort4*)(Xb + (size_t)p2.x * 128 + cl * 4);
            ushort4 v3 = *(const ushort4*)(Xb + (size_t)p3.x * 128 + cl * 4);
            acc.x = fmaf(w0, bf2f(v0.x), acc.x); acc.y = fmaf(w0, bf2f(v0.y), acc.y);
            acc.z = fmaf(w0, bf2f(v0.z), acc.z); acc.w = fmaf(w0, bf2f(v0.w), acc.w);
            acc.x = fmaf(w1, bf2f(v1.x), acc.x); acc.y = fmaf(w1, bf2f(v1.y), acc.y);
            acc.z = fmaf(w1, bf2f(v1.z), acc.z); acc.w = fmaf(w1, bf2f(v1.w), acc.w);
            acc.x = fmaf(w2, bf2f(v2.x), acc.x); acc.y = fmaf(w2, bf2f(v2.y), acc.y);
            acc.z = fmaf(w2, bf2f(v2.z), acc.z); acc.w = fmaf(w2, bf2f(v2.w), acc.w);
            acc.x = fmaf(w3, bf2f(v3.x), acc.x); acc.y = fmaf(w3, bf2f(v3.y), acc.y);
            acc.z = fmaf(w3, bf2f(v3.z), acc.z); acc.w = fmaf(w3, bf2f(v3.w), acc.w);
        }
        for (; i < end; ++i) {
            int2 pk = edges_b[i];
            float w = __int_as_float(pk.y);
            ushort4 v = *(const ushort4*)(Xb + (size_t)pk.x * 128 + cl * 4);
            acc.x = fmaf(w, bf2f(v.x), acc.x); acc.y = fmaf(w, bf2f(v.y), acc.y);
            acc.z = fmaf(w, bf2f(v.z), acc.z); acc.w = fmaf(w, bf2f(v.w), acc.w);
        }
        ushort4 st;
        st.x = f2bf(acc.x); st.y = f2bf(acc.y);
        st.z = f2bf(acc.z); st.w = f2bf(acc.w);
        *(ushort4*)(agg2 + (size_t)node * 128 + cl * 4) = st;
    }
}

// ---------------- gather3: bf16 movie rows -> bf16 agg3, weighted ----------
__global__ __launch_bounds__(256)
void gather3_kernel(const u16* __restrict__ Mv, const int2* __restrict__ edges_b,
                    const int* __restrict__ rp_b, u16* __restrict__ agg3, int ND)
{
    const int node = blockIdx.x * 8 + (threadIdx.x >> 5);
    if (node >= ND) return;
    const int cl = threadIdx.x & 31;
    int i   = rp_b[node];
    int end = rp_b[node + 1];

    float4 acc = make_float4(0.f, 0.f, 0.f, 0.f);
    for (; i + 4 <= end; i += 4) {
        int2 p0 = edges_b[i],     p1 = edges_b[i + 1];
        int2 p2 = edges_b[i + 2], p3 = edges_b[i + 3];
        float w0 = __int_as_float(p0.y), w1 = __int_as_float(p1.y);
        float w2 = __int_as_float(p2.y), w3 = __int_as_float(p3.y);
        ushort4 v0 = *(const ushort4*)(Mv + (size_t)p0.x * 128 + cl * 4);
        ushort4 v1 = *(const ushort4*)(Mv + (size_t)p1.x * 128 + cl * 4);
        ushort4 v2 = *(const ushort4*)(Mv + (size_t)p2.x * 128 + cl * 4);
        ushort4 v3 = *(const ushort4*)(Mv + (size_t)p3.x * 128 + cl * 4);
        acc.x = fmaf(w0, bf2f(v0.x), acc.x); acc.y = fmaf(w0, bf2f(v0.y), acc.y);
        acc.z = fmaf(w0, bf2f(v0.z), acc.z); acc.w = fmaf(w0, bf2f(v0.w), acc.w);
        acc.x = fmaf(w1, bf2f(v1.x), acc.x); acc.y = fmaf(w1, bf2f(v1.y), acc.y);
        acc.z = fmaf(w1, bf2f(v1.z), acc.z); acc.w = fmaf(w1, bf2f(v1.w), acc.w);
        acc.x = fmaf(w2, bf2f(v2.x), acc.x); acc.y = fmaf(w2, bf2f(v2.y), acc.y);
        acc.z = fmaf(w2, bf2f(v2.z), acc.z); acc.w = fmaf(w2, bf2f(v2.w), acc.w);
        acc.x = fmaf(w3, bf2f(v3.x), acc.x); acc.y = fmaf(w3, bf2f(v3.y), acc.y);
        acc.z = fmaf(w3, bf2f(v3.z), acc.z); acc.w = fmaf(w3, bf2f(v3.w), acc.w);
    }
    for (; i < end; ++i) {
        int2 pk = edges_b[i];
        float w = __int_as_float(pk.y);
        ushort4 v = *(const ushort4*)(Mv + (size_t)pk.x * 128 + cl * 4);
        acc.x = fmaf(w, bf2f(v.x), acc.x); acc.y = fmaf(w, bf2f(v.y), acc.y);
        acc.z = fmaf(w, bf2f(v.z), acc.z); acc.w = fmaf(w, bf2f(v.w), acc.w);
    }
    ushort4 st;
    st.x = f2bf(acc.x); st.y = f2bf(acc.y);
    st.z = f2bf(acc.z); st.w = f2bf(acc.w);
    *(ushort4*)(agg3 + (size_t)node * 128 + cl * 4) = st;
}

// ---------------- merged MFMA conv1+conv2 (bf16 A, two-stage 32KB W) --------
// No early returns: barriers mid-kernel; rows clamped, stores guarded.
__global__ __launch_bounds__(256)
void conv12_mfma(const u16* __restrict__ agg1, const u16* __restrict__ w1r,
                 const float* __restrict__ b1, const u16* __restrict__ xm_bf,
                 const u16* __restrict__ w1o, u16* __restrict__ C1, int N1, int cb1,
                 const u16* __restrict__ agg2, const u16* __restrict__ w2r,
                 const float* __restrict__ b2, const u16* __restrict__ xd_bf,
                 const u16* __restrict__ w2o, u16* __restrict__ C2, int N2)
{
    __shared__ u16 sW[16384];   // 32 KB, one phase at a time

    const bool seg1 = (int)blockIdx.x < cb1;
    const u16 *A0, *A1p, *Wr, *Wo; const float* bias; u16* C; int N, base;
    if (seg1) { A0 = agg1; A1p = xm_bf; Wr = w1r; Wo = w1o; bias = b1; C = C1; N = N1; base = blockIdx.x; }
    else      { A0 = agg2; A1p = xd_bf; Wr = w2r; Wo = w2o; bias = b2; C = C2; N = N2; base = blockIdx.x - cb1; }

    const int tid  = threadIdx.x;
    const int lane = tid & 63;
    const int m0   = (base * 4 + (tid >> 6)) * 32;
    const int lr   = lane & 15;
    const int quad = lane >> 4;

    int r0 = m0 + lr;      if (r0 >= N) r0 = N - 1;
    int r1 = m0 + 16 + lr; if (r1 >= N) r1 = N - 1;

    f32x4 acc[2][8];
#pragma unroll
    for (int mt = 0; mt < 2; ++mt)
#pragma unroll
        for (int n = 0; n < 8; ++n) acc[mt][n] = (f32x4){0.f, 0.f, 0.f, 0.f};

    // phase 0: aggregate term
    for (int i = tid; i < 2048; i += 256)
        ((uint4*)sW)[i] = ((const uint4*)Wr)[i];
    __syncthreads();
#pragma unroll
    for (int c = 0; c < 4; ++c) {
        const int kb = c * 32 + quad * 8;
        bf16x8 a0 = *(const bf16x8*)(A0 + (size_t)r0 * 128 + kb);
        bf16x8 a1 = *(const bf16x8*)(A0 + (size_t)r1 * 128 + kb);
        const u16* wp = sW + c * 4096 + lane * 8;
#pragma unroll
        for (int n = 0; n < 8; ++n) {
            bf16x8 b = *(const bf16x8*)(wp + n * 512);
            acc[0][n] = __builtin_amdgcn_mfma_f32_16x16x32_bf16(a0, b, acc[0][n], 0, 0, 0);
            acc[1][n] = __builtin_amdgcn_mfma_f32_16x16x32_bf16(a1, b, acc[1][n], 0, 0, 0);
        }
    }
    __syncthreads();

    // phase 1: root term
    for (int i = tid; i < 2048; i += 256)
        ((uint4*)sW)[i] = ((const uint4*)Wo)[i];
    __syncthreads();
#pragma unroll
    for (int c = 0; c < 4; ++c) {
        const int kb = c * 32 + quad * 8;
        bf16x8 a0 = *(const bf16x8*)(A1p + (size_t)r0 * 128 + kb);
        bf16x8 a1 = *(const bf16x8*)(A1p + (size_t)r1 * 128 + kb);
        const u16* wp = sW + c * 4096 + lane * 8;
#pragma unroll
        for (int n = 0; n < 8; ++n) {
            bf16x8 b = *(const bf16x8*)(wp + n * 512);
            acc[0][n] = __builtin_amdgcn_mfma_f32_16x16x32_bf16(a0, b, acc[0][n], 0, 0, 0);
            acc[1][n] = __builtin_amdgcn_mfma_f32_16x16x32_bf16(a1, b, acc[1][n], 0, 0, 0);
        }
    }

#pragma unroll
    for (int mt = 0; mt < 2; ++mt) {
#pragma unroll
        for (int n = 0; n < 8; ++n) {
            const int col = n * 16 + lr;
            const float b = bias[col];
#pragma unroll
            for (int r = 0; r < 4; ++r) {
                int row = m0 + mt * 16 + quad * 4 + r;
                if (row >= N) continue;
                C[(size_t)row * 128 + col] = f2bf(fmaxf(acc[mt][n][r] + b, 0.f));
            }
        }
    }
}

// ---------------- conv3 + lin fused (bf16 A), 50 KB LDS ----------------
__global__ __launch_bounds__(256)
void conv3_lin(const u16* __restrict__ A1, const u16* __restrict__ Wr,
               const float* __restrict__ bias3,
               const u16* __restrict__ A2, const u16* __restrict__ Wo,
               const u16* __restrict__ Wl, const float* __restrict__ bias_l,
               float* __restrict__ out, int N)
{
    __shared__ u16 lds[17408 + 8192];   // 34 KB tile region (overlays conv W) + 16 KB lin W
    u16* tile = lds;
    u16* sWl  = lds + 17408;

    const int tid  = threadIdx.x;
    const int lane = tid & 63;
    const int wv   = tid >> 6;
    const int wbase = wv * 32;
    const int m0   = (blockIdx.x * 4 + wv) * 32;
    const int lr   = lane & 15;
    const int quad = lane >> 4;

    int r0 = m0 + lr;      if (r0 >= N) r0 = N - 1;
    int r1 = m0 + 16 + lr; if (r1 >= N) r1 = N - 1;

    f32x4 acc[2][8];
#pragma unroll
    for (int mt = 0; mt < 2; ++mt)
#pragma unroll
        for (int n = 0; n < 8; ++n) acc[mt][n] = (f32x4){0.f, 0.f, 0.f, 0.f};

    // stage lin W once + conv phase-0 W
    for (int i = tid; i < 1024; i += 256)
        ((uint4*)sWl)[i] = ((const uint4*)Wl)[i];
    for (int i = tid; i < 2048; i += 256)
        ((uint4*)lds)[i] = ((const uint4*)Wr)[i];
    __syncthreads();
#pragma unroll
    for (int c = 0; c < 4; ++c) {
        const int kb = c * 32 + quad * 8;
        bf16x8 a0 = *(const bf16x8*)(A1 + (size_t)r0 * 128 + kb);
        bf16x8 a1 = *(const bf16x8*)(A1 + (size_t)r1 * 128 + kb);
        const u16* wp = lds + c * 4096 + lane * 8;
#pragma unroll
        for (int n = 0; n < 8; ++n) {
            bf16x8 b = *(const bf16x8*)(wp + n * 512);
            acc[0][n] = __builtin_amdgcn_mfma_f32_16x16x32_bf16(a0, b, acc[0][n], 0, 0, 0);
            acc[1][n] = __builtin_amdgcn_mfma_f32_16x16x32_bf16(a1, b, acc[1][n], 0, 0, 0);
        }
    }
    __syncthreads();
    for (int i = tid; i < 2048; i += 256)
        ((uint4*)lds)[i] = ((const uint4*)Wo)[i];
    __syncthreads();
#pragma unroll
    for (int c = 0; c < 4; ++c) {
        const int kb = c * 32 + quad * 8;
        bf16x8 a0 = *(const bf16x8*)(A2 + (size_t)r0 * 128 + kb);
        bf16x8 a1 = *(const bf16x8*)(A2 + (size_t)r1 * 128 + kb);
        const u16* wp = lds + c * 4096 + lane * 8;
#pragma unroll
        for (int n = 0; n < 8; ++n) {
            bf16x8 b = *(const bf16x8*)(wp + n * 512);
            acc[0][n] = __builtin_amdgcn_mfma_f32_16x16x32_bf16(a0, b, acc[0][n], 0, 0, 0);
            acc[1][n] = __builtin_amdgcn_mfma_f32_16x16x32_bf16(a1, b, acc[1][n], 0, 0, 0);
        }
    }
    __syncthreads();   // done reading conv W; tile overlays it

    // relu'd bf16 tile, C-layout -> padded rows (pitch 136)
#pragma unroll
    for (int mt = 0; mt < 2; ++mt) {
#pragma unroll
        for (int n = 0; n < 8; ++n) {
            const int col = n * 16 + lr;
            const float b = bias3[col];
#pragma unroll
            for (int r = 0; r < 4; ++r) {
                int row = wbase + mt * 16 + quad * 4 + r;
                tile[row * 136 + col] = f2bf(fmaxf(acc[mt][n][r] + b, 0.f));
            }
        }
    }
    __syncthreads();

    f32x4 acc2[2][4];
#pragma unroll
    for (int mt = 0; mt < 2; ++mt)
#pragma unroll
        for (int n = 0; n < 4; ++n) acc2[mt][n] = (f32x4){0.f, 0.f, 0.f, 0.f};

#pragma unroll
    for (int c = 0; c < 4; ++c) {
        const int kb = c * 32 + quad * 8;
        bf16x8 a0 = *(const bf16x8*)(tile + (wbase + lr) * 136 + kb);
        bf16x8 a1 = *(const bf16x8*)(tile + (wbase + 16 + lr) * 136 + kb);
#pragma unroll
        for (int n = 0; n < 4; ++n) {
            bf16x8 b = *(const bf16x8*)(sWl + c * 2048 + n * 512 + lane * 8);
            acc2[0][n] = __builtin_amdgcn_mfma_f32_16x16x32_bf16(a0, b, acc2[0][n], 0, 0, 0);
            acc2[1][n] = __builtin_amdgcn_mfma_f32_16x16x32_bf16(a1, b, acc2[1][n], 0, 0, 0);
        }
    }

#pragma unroll
    for (int mt = 0; mt < 2; ++mt) {
#pragma unroll
        for (int n = 0; n < 4; ++n) {
            const int col = n * 16 + lr;
            const float b = bias_l[col];
#pragma unroll
            for (int r = 0; r < 4; ++r) {
                int row = m0 + mt * 16 + quad * 4 + r;
                if (row >= N) continue;
                out[(size_t)row * 64 + col] = acc2[mt][n][r] + b;
            }
        }
    }
}

extern "C" void kernel_launch(void* const* d_in, const int* in_sizes, int n_in,
                              void* d_out, int out_size, void* d_ws, size_t ws_size,
                              hipStream_t stream)
{
    const float* x_meas  = (const float*)d_in[0];
    const float* x_dem   = (const float*)d_in[1];
    const int*   src_m   = (const int*)d_in[2];
    const int*   dst_m   = (const int*)d_in[3];
    const int*   src_b   = (const int*)d_in[4];
    const int*   dst_b   = (const int*)d_in[5];
    const float* edge_w  = (const float*)d_in[6];
    const float* W_rel1  = (const float*)d_in[7];
    const float* b_rel1  = (const float*)d_in[8];
    const float* W_root1 = (const float*)d_in[9];
    const float* W_rel2  = (const float*)d_in[10];
    const float* b_rel2  = (const float*)d_in[11];
    const float* W_root2 = (const float*)d_in[12];
    const float* W_rel3  = (const float*)d_in[13];
    const float* b_rel3  = (const float*)d_in[14];
    const float* W_root3 = (const float*)d_in[15];
    const float* W_lin   = (const float*)d_in[16];
    const float* b_lin   = (const float*)d_in[17];
    float* out = (float*)d_out;

    const int NM = NMC, ND = NDC, E = EC;

    char* p = (char*)d_ws;
    auto alloc = [&](size_t bytes) { char* r = p; p += (bytes + 511) & ~(size_t)511; return r; };
    u32*   histm   = (u32*)alloc((size_t)CM * NWM * 4);   // 6.4 MB
    u32*   histd   = (u32*)alloc((size_t)CD * NWD * 4);   // 1.28 MB
    int*   deg_m   = (int*)alloc((size_t)NM * 4);
    int*   deg_b   = (int*)alloc((size_t)ND * 4);
    int*   rp_m    = (int*)alloc((size_t)(NM + 1) * 4);
    int*   rp_b    = (int*)alloc((size_t)(ND + 1) * 4);
    int*   srcs_m  = (int*)alloc((size_t)E * 4);
    int2*  edges_b = (int2*)alloc((size_t)E * 8);
    u16*   agg1    = (u16*)alloc((size_t)NM * 128 * 2);   // 12.8 MB bf16
    u16*   agg2    = (u16*)alloc((size_t)ND * 128 * 2);   // 5.12 MB
    u16*   movie   = (u16*)alloc((size_t)NM * 128 * 2);   // 12.8 MB (= xm_bf alias)
    u16*   t2      = (u16*)alloc((size_t)ND * 128 * 2);   // 5.12 MB
    u16*   xd_bf   = (u16*)alloc((size_t)ND * 128 * 2);   // 5.12 MB
    u16*   wbuf    = (u16*)alloc(7 * 16384 * 2);          // 224 KB
    // aliases (stream-serial lifetimes):
    int* rank_m = (int*)agg1;          // dies at fill; agg1 written by gather12
    int* rank_b = rank_m + E;          // 4.8 MB total <= 12.8 MB
    u16* xm_bf  = movie;               // conv1 reads own rows, writes own rows (safe)
    u16* agg3   = agg1;                // agg1 dead after conv12

    const int TB  = (NM * 16 + 255) / 256;     // 3125
    const int TB2 = (ND * 16 + 255) / 256;     // 1250
    const int WB  = 448;
    const int HB  = (2 * E + 255) / 256;       // 4688 (fill grid)

    hist_lds<<<CM + CD, 256, 0, stream>>>(dst_m, dst_b, rank_m, rank_b, histm, histd);

    prep2<<<TB + TB2 + WB, 256, 0, stream>>>(
        x_meas, xm_bf, NM * 16, x_dem, xd_bf, ND * 16,
        W_rel1, W_root1, W_rel2, W_root2, W_rel3, W_root3, W_lin, wbuf,
        TB, TB2);

    basescan2<<<(NWM + NWD + 255) / 256, 256, 0, stream>>>(histm, histd, deg_m, deg_b);
    scan2_kernel<<<2, 1024, 0, stream>>>(deg_m, rp_m, NM, deg_b, rp_b, ND);
    fill_kernel<<<HB, 256, 0, stream>>>(src_m, dst_m, src_b, dst_b, edge_w,
                                        rp_m, rp_b, rank_m, rank_b,
                                        histm, histd, srcs_m, edges_b, E);

    gather12<<<(NM + ND + 7) / 8, 256, 0, stream>>>(xm_bf, srcs_m, edges_b,
                                                    rp_m, rp_b, agg1, agg2, NM, ND);

    const int cb1 = (NM + 127) / 128;
    const int cb2 = (ND + 127) / 128;
    u16* w1r = wbuf + 0 * 16384; u16* w1o = wbuf + 1 * 16384;
    u16* w2r = wbuf + 2 * 16384; u16* w2o = wbuf + 3 * 16384;
    u16* w3r = wbuf + 4 * 16384; u16* w3o = wbuf + 5 * 16384;
    u16* wl  = wbuf + 6 * 16384;
    conv12_mfma<<<cb1 + cb2, 256, 0, stream>>>(agg1, w1r, b_rel1, xm_bf, w1o, movie, NM, cb1,
                                               agg2, w2r, b_rel2, xd_bf, w2o, t2,    ND);

    gather3_kernel<<<(ND + 7) / 8, 256, 0, stream>>>(movie, edges_b, rp_b, agg3, ND);

    conv3_lin<<<cb2, 256, 0, stream>>>(agg3, w3r, b_rel3, t2, w3o, wl, b_lin, out, ND);
}